// Round 1
// baseline (656.018 us; speedup 1.0000x reference)
//
#include <hip/hip_runtime.h>

// GraphSAGE 3-layer (mean agg), N=100000 nodes, E=1600000 edges, 128->32->32->16.
// Strategy: project-then-aggregate (linearity of mean), atomics-based scatter.

#define BLOCK 256

// ---------------- degree ----------------
__global__ void degree_kernel(const int* __restrict__ dst, int* __restrict__ deg, int n_edges) {
    int e = blockIdx.x * blockDim.x + threadIdx.x;
    if (e < n_edges) atomicAdd(&deg[dst[e]], 1);
}

__global__ void invdeg_kernel(float* __restrict__ buf, int n_nodes) {
    int i = blockIdx.x * blockDim.x + threadIdx.x;
    if (i >= n_nodes) return;
    int d = ((const int*)buf)[i];
    float dd = (float)(d < 1 ? 1 : d);
    buf[i] = 1.0f / dd;   // in-place int -> float inverse-degree
}

// ---------------- fused projection: pre = h@Wself + b ; p = h@Wneigh ----------------
template<int DIN, int DOUT>
__global__ void proj_kernel(const float* __restrict__ h,
                            const float* __restrict__ Wself,
                            const float* __restrict__ Wneigh,
                            const float* __restrict__ bias,
                            float* __restrict__ pre,
                            float* __restrict__ p,
                            int n_nodes) {
    __shared__ float sWs[DIN * DOUT];
    __shared__ float sWn[DIN * DOUT];
    __shared__ float sb[DOUT];
    for (int i = threadIdx.x; i < DIN * DOUT; i += blockDim.x) {
        sWs[i] = Wself[i];
        sWn[i] = Wneigh[i];
    }
    if (threadIdx.x < DOUT) sb[threadIdx.x] = bias[threadIdx.x];
    __syncthreads();

    int idx = blockIdx.x * blockDim.x + threadIdx.x;   // over n_nodes * DOUT
    int node = idx / DOUT;
    int f    = idx % DOUT;
    if (node >= n_nodes) return;

    const float* __restrict__ row = h + (size_t)node * DIN;
    float accS = 0.f, accN = 0.f;
#pragma unroll 8
    for (int k = 0; k < DIN; ++k) {
        float x = row[k];                 // broadcast within the 32/16-lane group
        accS = fmaf(x, sWs[k * DOUT + f], accS);
        accN = fmaf(x, sWn[k * DOUT + f], accN);
    }
    pre[idx] = accS + sb[f];
    p[idx]   = accN;
}

// ---------------- edge scatter: agg[dst] += p[src] ----------------
template<int D>
__global__ void scatter_kernel(const float* __restrict__ p,
                               const int* __restrict__ src,
                               const int* __restrict__ dst,
                               float* __restrict__ agg,
                               int n_edges) {
    int idx = blockIdx.x * blockDim.x + threadIdx.x;   // over n_edges * D
    int e = idx / D;
    int f = idx % D;
    if (e >= n_edges) return;
    int s = src[e];
    int d = dst[e];
    atomicAdd(&agg[(size_t)d * D + f], p[(size_t)s * D + f]);
}

// ---------------- finalize: out = act(pre + agg * invdeg) ----------------
template<int D, bool RELU>
__global__ void finalize_kernel(const float* __restrict__ pre,
                                const float* __restrict__ agg,
                                const float* __restrict__ invdeg,
                                float* __restrict__ out,
                                int n_nodes) {
    int idx = blockIdx.x * blockDim.x + threadIdx.x;   // over n_nodes * D
    if (idx >= n_nodes * D) return;
    int node = idx / D;
    float v = pre[idx] + agg[idx] * invdeg[node];
    if (RELU) v = fmaxf(v, 0.f);
    out[idx] = v;
}

extern "C" void kernel_launch(void* const* d_in, const int* in_sizes, int n_in,
                              void* d_out, int out_size, void* d_ws, size_t ws_size,
                              hipStream_t stream) {
    const float* x        = (const float*)d_in[0];
    const int*   edge_src = (const int*)d_in[1];
    const int*   edge_dst = (const int*)d_in[2];
    const float* Ws1 = (const float*)d_in[3];
    const float* Wn1 = (const float*)d_in[4];
    const float* b1  = (const float*)d_in[5];
    const float* Ws2 = (const float*)d_in[6];
    const float* Wn2 = (const float*)d_in[7];
    const float* b2  = (const float*)d_in[8];
    const float* Ws3 = (const float*)d_in[9];
    const float* Wn3 = (const float*)d_in[10];
    const float* b3  = (const float*)d_in[11];
    float* out = (float*)d_out;

    const int IN = 128, HID = 32, OUT = 16;
    const int n_nodes = in_sizes[0] / IN;
    const int n_edges = in_sizes[1];

    // workspace layout (floats)
    float* ws = (float*)d_ws;
    size_t off = 0;
    float* invdeg = ws + off; off += (size_t)n_nodes;          // also used as int deg
    // align to 256 floats
    off = (off + 255) & ~(size_t)255;
    float* B0 = ws + off; off += (size_t)n_nodes * HID;        // pre
    float* B1 = ws + off; off += (size_t)n_nodes * HID;        // p / h2
    float* B2 = ws + off; off += (size_t)n_nodes * HID;        // agg
    float* B3 = ws + off; off += (size_t)n_nodes * HID;        // h1 / p3

    const int gEdges = (n_edges + BLOCK - 1) / BLOCK;
    const int gNodes = (n_nodes + BLOCK - 1) / BLOCK;
    const int gN32   = ((size_t)n_nodes * 32 + BLOCK - 1) / BLOCK;
    const int gN16   = ((size_t)n_nodes * 16 + BLOCK - 1) / BLOCK;
    const int gE32   = ((size_t)n_edges * 32 + BLOCK - 1) / BLOCK;
    const int gE16   = ((size_t)n_edges * 16 + BLOCK - 1) / BLOCK;

    // ---- degree (once) ----
    hipMemsetAsync(invdeg, 0, (size_t)n_nodes * sizeof(int), stream);
    degree_kernel<<<gEdges, BLOCK, 0, stream>>>(edge_dst, (int*)invdeg, n_edges);
    invdeg_kernel<<<gNodes, BLOCK, 0, stream>>>(invdeg, n_nodes);

    // ---- layer 1: 128 -> 32, relu ----
    proj_kernel<128, 32><<<gN32, BLOCK, 0, stream>>>(x, Ws1, Wn1, b1, B0, B1, n_nodes);
    hipMemsetAsync(B2, 0, (size_t)n_nodes * 32 * sizeof(float), stream);
    scatter_kernel<32><<<gE32, BLOCK, 0, stream>>>(B1, edge_src, edge_dst, B2, n_edges);
    finalize_kernel<32, true><<<gN32, BLOCK, 0, stream>>>(B0, B2, invdeg, B3, n_nodes);

    // ---- layer 2: 32 -> 32, relu ----
    proj_kernel<32, 32><<<gN32, BLOCK, 0, stream>>>(B3, Ws2, Wn2, b2, B0, B1, n_nodes);
    hipMemsetAsync(B2, 0, (size_t)n_nodes * 32 * sizeof(float), stream);
    scatter_kernel<32><<<gE32, BLOCK, 0, stream>>>(B1, edge_src, edge_dst, B2, n_edges);
    finalize_kernel<32, true><<<gN32, BLOCK, 0, stream>>>(B0, B2, invdeg, B1, n_nodes);  // h2 -> B1

    // ---- layer 3: 32 -> 16, no relu ----
    proj_kernel<32, 16><<<gN16, BLOCK, 0, stream>>>(B1, Ws3, Wn3, b3, B0, B3, n_nodes); // p3 -> B3
    hipMemsetAsync(B2, 0, (size_t)n_nodes * 16 * sizeof(float), stream);
    scatter_kernel<16><<<gE16, BLOCK, 0, stream>>>(B3, edge_src, edge_dst, B2, n_edges);
    finalize_kernel<16, false><<<gN16, BLOCK, 0, stream>>>(B0, B2, invdeg, out, n_nodes);
}